// Round 6
// baseline (198.107 us; speedup 1.0000x reference)
//
#include <hip/hip_runtime.h>

#define HWD 256
#define NB 2
#define NV 5023
#define NF 2048

// ws layout:
//  frP     @ 0x000000  4096 * 64B = 256 KiB  (16 floats per face, batch-major)
//  vattr   @ 0x040000  10046*6*4B = 236 KiB  (region 256 KiB)
//  rFace   @ 0x080000  4096 * 64B = 256 KiB  (rank-ordered face records)
//  binData @ 0x0C0000  4096 * 48B = 192 KiB  (rank-ordered bin test data)
//  list    @ 0x0F0000  512 * 2048 * 2B = 2 MiB  (per 16x16 tile, rank-sorted)
//  listCnt @ 0x2F0000  512 * 4B

__device__ __forceinline__ float pix_coord(int i) {
    return ((float)i + 0.5f) * 0.0078125f - 1.0f;   // exact fp32
}

// frP fields: 0 dy12, 1 dx21, 2 x2, 3 y2, 4 dy20, 5 dx02, 6 inv, 7 z0, 8 z1, 9 z2,
//             10 bbx, 11 bby, 12 denom, 13 zmax
__global__ __launch_bounds__(256) void k_prep(const float* __restrict__ verts,
                                              const float* __restrict__ tex,
                                              const float* __restrict__ uv,
                                              const float* __restrict__ tv,
                                              const int* __restrict__ faces,
                                              float* __restrict__ frP,
                                              float* __restrict__ vattr) {
    int blk = blockIdx.x, tid = threadIdx.x;
    if (blk < 40) {                       // ---- per-vertex attributes ----
        int i = blk * 256 + tid;
        if (i >= NB * NV) return;
        int b = i / NV, v = i - b * NV;
        float u = __fmul_rn(uv[2 * v + 0], 255.0f);
        float w = __fmul_rn(uv[2 * v + 1], 255.0f);
        float uf = floorf(u); uf = fminf(fmaxf(uf, 0.0f), 254.0f);
        float vf = floorf(w); vf = fminf(fmaxf(vf, 0.0f), 254.0f);
        int u0 = (int)uf, v0 = (int)vf;
        float fu = __fsub_rn(u, uf);
        float fv = __fsub_rn(w, vf);
        const float* t   = tex + (size_t)b * HWD * HWD * 3;
        const float* c00 = t + ((size_t)v0 * HWD + u0) * 3;
        const float* c01 = c00 + 3;
        const float* c10 = c00 + HWD * 3;
        const float* c11 = c10 + 3;
        float gu = 1.0f - fu, gv = 1.0f - fv;
        float* o = vattr + (size_t)i * 6;
        for (int c = 0; c < 3; ++c) {
            float l0 = c00[c] * gu + c01[c] * fu;
            float l1 = c10[c] * gu + c11[c] * fu;
            o[c] = l0 * gv + l1 * fv;
        }
        const float* vp = verts + ((size_t)b * NV + v) * 3;
        o[3] = vp[0]; o[4] = vp[1]; o[5] = vp[2];
        return;
    }
    // ---- per-face setup ----
    int i = (blk - 40) * 256 + tid;
    if (i >= NB * NF) return;
    int b = i / NF, f = i - b * NF;
    int i0 = faces[3 * f + 0], i1 = faces[3 * f + 1], i2 = faces[3 * f + 2];
    const float* base = tv + (size_t)b * NV * 3;
    float x0 = base[3 * i0 + 0], y0 = base[3 * i0 + 1], z0 = base[3 * i0 + 2];
    float x1 = base[3 * i1 + 0], y1 = base[3 * i1 + 1], z1 = base[3 * i1 + 2];
    float x2 = base[3 * i2 + 0], y2 = base[3 * i2 + 1], z2 = base[3 * i2 + 2];

    float dy12 = __fsub_rn(y1, y2);
    float dx21 = __fsub_rn(x2, x1);
    float dy20 = __fsub_rn(y2, y0);
    float dx02 = __fsub_rn(x0, x2);
    float denom = __fadd_rn(__fmul_rn(dy12, __fsub_rn(x0, x2)),
                            __fmul_rn(dx21, __fsub_rn(y0, y2)));
    bool valid = fabsf(denom) > 1e-8f;

    int xlo = 1, xhi = 0, ylo = 1, yhi = 0;
    if (valid) {
        if (fabsf(denom) < 1e-3f) {
            xlo = 0; xhi = 255; ylo = 0; yhi = 255;
        } else {
            float xmn = fminf(x0, fminf(x1, x2)), xmx = fmaxf(x0, fmaxf(x1, x2));
            float ymn = fminf(y0, fminf(y1, y2)), ymx = fmaxf(y0, fmaxf(y1, y2));
            xlo = (int)floorf((xmn + 1.0f) * 128.0f - 0.5f) - 1;
            xhi = (int)ceilf ((xmx + 1.0f) * 128.0f - 0.5f) + 1;
            ylo = (int)floorf((ymn + 1.0f) * 128.0f - 0.5f) - 1;
            yhi = (int)ceilf ((ymx + 1.0f) * 128.0f - 0.5f) + 1;
            xlo = max(xlo, 0); ylo = max(ylo, 0);
            xhi = min(xhi, 255); yhi = min(yhi, 255);
            if (xhi < xlo || yhi < ylo) { xlo = 1; xhi = 0; ylo = 1; yhi = 0; }
        }
    }
    float* o = frP + (size_t)i * 16;
    o[0] = dy12; o[1] = dx21; o[2] = x2; o[3] = y2;
    o[4] = dy20; o[5] = dx02; o[6] = valid ? (1.0f / denom) : 0.0f;
    o[7] = z0; o[8] = z1; o[9] = z2;
    ((unsigned int*)o)[10] = (unsigned)xlo | ((unsigned)xhi << 16);
    ((unsigned int*)o)[11] = (unsigned)ylo | ((unsigned)yhi << 16);
    o[12] = denom;
    o[13] = valid ? fmaxf(z0, fmaxf(z1, z2)) : -2.0f;
}

// sort faces by zmax desc (bitonic, per batch); emit rank-ordered rFace + binData
// rFace[rank] (16 floats): 0 bbx, 1 bby, 2 fid-bits, 3 zmax,
//                          4 dy12, 5 dx21, 6 x2, 7 y2, 8 dy20, 9 dx02, 10 inv,
//                          11 z0, 12 z1, 13 z2, 14 0, 15 0
__global__ __launch_bounds__(1024) void k_sort(const float* __restrict__ frP,
                                               float* __restrict__ rFace,
                                               float* __restrict__ binData) {
    int b = blockIdx.x, tid = threadIdx.x;
    __shared__ unsigned long long key[NF];
    for (int i = tid; i < NF; i += 1024) {
        float zmax = frP[(((size_t)(b * NF + i)) << 4) + 13];
        unsigned int ub = __float_as_uint(zmax);
        unsigned int zo = (ub & 0x80000000u) ? ~ub : (ub | 0x80000000u);
        key[i] = ((unsigned long long)zo << 16) | (unsigned)i;
    }
    __syncthreads();
    for (int k = 2; k <= NF; k <<= 1) {
        for (int j = k >> 1; j > 0; j >>= 1) {
            for (int i = tid; i < NF; i += 1024) {
                int ixj = i ^ j;
                if (ixj > i) {
                    unsigned long long a = key[i], c = key[ixj];
                    bool sw = ((i & k) == 0) ? (a < c) : (a > c);   // descending
                    if (sw) { key[i] = c; key[ixj] = a; }
                }
            }
            __syncthreads();
        }
    }
    for (int r = tid; r < NF; r += 1024) {
        int fid = (int)(key[r] & 0xFFFFu);
        const float* o = frP + (((size_t)(b * NF + fid)) << 4);
        float* rf = rFace + (((size_t)(b * NF + r)) << 4);
        rf[0] = o[10]; rf[1] = o[11];
        rf[2] = __uint_as_float((unsigned)fid);
        rf[3] = o[13];
        for (int c = 0; c < 10; ++c) rf[4 + c] = o[c];
        rf[14] = 0.0f; rf[15] = 0.0f;

        float inv = o[6];
        float A0 = o[0] * inv, B0 = o[1] * inv;
        float A1 = o[4] * inv, B1 = o[5] * inv;
        float* bd = binData + (size_t)(b * NF + r) * 12;
        bd[0] = o[10]; bd[1] = o[11];
        bd[2] = A0; bd[3] = B0; bd[4] = A1; bd[5] = B1;
        bd[6] = A0 + A1; bd[7] = B0 + B1;
        bd[8] = o[2]; bd[9] = o[3];
        bd[10] = (fabsf(o[12]) < 1e-3f) ? 1.0f : 0.0f;
        bd[11] = 0.0f;
    }
}

// one wave per (b,16x16 tile): scan sorted ranks, ballot-compact (ordered, no atomics)
__global__ __launch_bounds__(64) void k_bin(const float* __restrict__ binData,
                                            unsigned short* __restrict__ list,
                                            unsigned int* __restrict__ listCnt) {
    int bt = blockIdx.x;
    int b = bt >> 8, tile = bt & 255;
    int lane = threadIdx.x;
    int tlx = tile & 15, tly = tile >> 4;
    float x0n = pix_coord(tlx * 16), x1n = pix_coord(tlx * 16 + 15);
    float y0n = pix_coord(tly * 16), y1n = pix_coord(tly * 16 + 15);
    unsigned int cnt = 0;
    unsigned short* lst = list + (size_t)bt * NF;
    for (int r = lane; r < NF; r += 64) {
        const float* bd = binData + (size_t)(b * NF + r) * 12;
        unsigned int bbx = __float_as_uint(bd[0]), bby = __float_as_uint(bd[1]);
        int xlo = (int)(bbx & 0xffffu), xhi = (int)(bbx >> 16);
        int ylo = (int)(bby & 0xffffu), yhi = (int)(bby >> 16);
        bool keep = (xhi >= xlo) && (tlx >= (xlo >> 4)) && (tlx <= (xhi >> 4))
                                 && (tly >= (ylo >> 4)) && (tly <= (yhi >> 4));
        if (keep && bd[10] == 0.0f) {
            float A0 = bd[2], B0 = bd[3], A1 = bd[4], B1 = bd[5];
            float C = bd[6], D = bd[7], x2 = bd[8], y2 = bd[9];
            float w0m = A0 * ((A0 > 0.f ? x1n : x0n) - x2) + B0 * ((B0 > 0.f ? y1n : y0n) - y2);
            float w1m = A1 * ((A1 > 0.f ? x1n : x0n) - x2) + B1 * ((B1 > 0.f ? y1n : y0n) - y2);
            float w2m = 1.0f - (C * ((C > 0.f ? x0n : x1n) - x2) + D * ((D > 0.f ? y0n : y1n) - y2));
            keep = (w0m >= -0.02f) && (w1m >= -0.02f) && (w2m >= -0.02f);
        }
        unsigned long long mask = __ballot(keep);
        if (keep) {
            int pos = cnt + __popcll(mask & ((1ull << lane) - 1ull));
            lst[pos] = (unsigned short)r;
        }
        cnt += __popcll(mask);
    }
    if (lane == 0) listCnt[bt] = cnt;
}

// one wave per (b, 8x8 quadrant): rank-sorted scan, early-z break, inline shade
__global__ __launch_bounds__(64) void k_raster(const float* __restrict__ rFace,
                                               const unsigned short* __restrict__ list,
                                               const unsigned int* __restrict__ listCnt,
                                               const int* __restrict__ faces,
                                               const float* __restrict__ vattr,
                                               float* __restrict__ out) {
    int bid  = blockIdx.x;                  // b*1024 + tile*4 + quad
    int quad = bid & 3;
    int tile = (bid >> 2) & 255;
    int b    = bid >> 10;
    int lane = threadIdx.x;

    int px0 = (tile & 15) * 16 + (quad & 1) * 8;
    int py0 = (tile >> 4) * 16 + (quad >> 1) * 8;
    int px = px0 + (lane & 7), py = py0 + (lane >> 3);
    float pxf = pix_coord(px), pyf = pix_coord(py);

    int bt = b * 256 + tile;
    unsigned int count = listCnt[bt];
    const unsigned short* lst = list + (size_t)bt * NF;
    const float* rB = rFace + (((size_t)b * NF) << 4);

    __shared__ __align__(16) float fdat[64 * 16];
    unsigned long long best = 0ull;
    float bw0 = 0.0f, bw1 = 0.0f, curz = -1.0f, tile_min = -1.0f;

    for (unsigned int c = 0; c < count; c += 64) {
        int n = (int)min(64u, count - c);
        __syncthreads();
        if (lane < n) {
            int r = lst[c + lane];
            const float4* src = (const float4*)(rB + ((size_t)r << 4));
            float4* dst = (float4*)&fdat[lane << 4];
            dst[0] = src[0]; dst[1] = src[1]; dst[2] = src[2]; dst[3] = src[3];
        }
        __syncthreads();
        if (fdat[3] < tile_min - 1e-5f) break;   // chunk zmax below every pixel's best

        for (int j = 0; j < n; ++j) {
            const float4 h = *(const float4*)&fdat[j << 4];
            unsigned int bbx = __float_as_uint(h.x), bby = __float_as_uint(h.y);
            int xlo = (int)(bbx & 0xffffu), xhi = (int)(bbx >> 16);
            int ylo = (int)(bby & 0xffffu), yhi = (int)(bby >> 16);
            if (xlo > px0 + 7 || xhi < px0 || ylo > py0 + 7 || yhi < py0) continue;
            const float4 g0 = *(const float4*)&fdat[(j << 4) + 4];   // dy12,dx21,x2,y2
            const float4 g1 = *(const float4*)&fdat[(j << 4) + 8];   // dy20,dx02,inv,z0
            float z1 = fdat[(j << 4) + 12], z2 = fdat[(j << 4) + 13];
            float t0 = __fsub_rn(pxf, g0.z);
            float t1 = __fsub_rn(pyf, g0.w);
            float w0 = __fmul_rn(__fadd_rn(__fmul_rn(g0.x, t0), __fmul_rn(g0.y, t1)), g1.z);
            float w1 = __fmul_rn(__fadd_rn(__fmul_rn(g1.x, t0), __fmul_rn(g1.y, t1)), g1.z);
            float w2 = __fsub_rn(__fsub_rn(1.0f, w0), w1);
            if (w0 >= 0.0f && w1 >= 0.0f && w2 >= 0.0f) {
                float z = __fadd_rn(__fadd_rn(__fmul_rn(w0, g1.w), __fmul_rn(w1, z1)),
                                    __fmul_rn(w2, z2));
                unsigned int ub = __float_as_uint(z);
                unsigned int hi = ub ^ ((unsigned int)(((int)ub) >> 31) | 0x80000000u);
                unsigned long long key = ((unsigned long long)hi << 32)
                                       | (unsigned long long)(0x7FFFFFFFu - __float_as_uint(h.z));
                if (key > best) { best = key; bw0 = w0; bw1 = w1; curz = z; }
            }
        }
        float m = curz;
        for (int off = 1; off < 64; off <<= 1) m = fminf(m, __shfl_xor(m, off));
        tile_min = m;
    }

    // ---- inline shade ----
    float img[6] = {0, 0, 0, 0, 0, 0};
    float alpha, fidf, zout;
    if (best == 0ull) {
        alpha = 0.0f; fidf = -1.0f; zout = -1.0f;
    } else {
        int f = (int)(0x7FFFFFFFu - (unsigned int)best);
        unsigned int hi = (unsigned int)(best >> 32);
        unsigned int zb32 = (hi & 0x80000000u) ? (hi & 0x7FFFFFFFu) : ~hi;
        zout = __uint_as_float(zb32);
        alpha = 1.0f;
        fidf = (float)f;
        float w2 = __fsub_rn(__fsub_rn(1.0f, bw0), bw1);
        int i0 = faces[3 * f + 0], i1 = faces[3 * f + 1], i2 = faces[3 * f + 2];
        const float* a0 = vattr + ((size_t)b * NV + i0) * 6;
        const float* a1 = vattr + ((size_t)b * NV + i1) * 6;
        const float* a2 = vattr + ((size_t)b * NV + i2) * 6;
        for (int c = 0; c < 6; ++c)
            img[c] = __fadd_rn(__fadd_rn(__fmul_rn(bw0, a0[c]), __fmul_rn(bw1, a1[c])),
                               __fmul_rn(w2, a2[c]));
    }

    int i = (b << 16) + py * HWD + px;
    const size_t plane = (size_t)HWD * HWD;
    int pix = py * HWD + px;
    for (int c = 0; c < 6; ++c)
        out[((size_t)b * 6 + c) * plane + pix] = img[c];
    out[786432 + i]  = alpha;
    out[917504 + i]  = fidf;
    out[1048576 + i] = zout;
}

extern "C" void kernel_launch(void* const* d_in, const int* in_sizes, int n_in,
                              void* d_out, int out_size, void* d_ws, size_t ws_size,
                              hipStream_t stream) {
    (void)in_sizes; (void)n_in; (void)out_size; (void)ws_size;
    const float* verts = (const float*)d_in[0];
    const float* tv    = (const float*)d_in[1];
    const float* tex   = (const float*)d_in[2];
    const float* uv    = (const float*)d_in[3];
    const int*   faces = (const int*)d_in[4];
    float* out = (float*)d_out;

    char* ws = (char*)d_ws;
    float*          frP     = (float*)ws;                         // 256 KiB
    float*          vattr   = (float*)(ws + 0x040000);            // 256 KiB
    float*          rFace   = (float*)(ws + 0x080000);            // 256 KiB
    float*          binData = (float*)(ws + 0x0C0000);            // 192 KiB
    unsigned short* list    = (unsigned short*)(ws + 0x0F0000);   // 2 MiB
    unsigned int*   listCnt = (unsigned int*)(ws + 0x2F0000);     // 2 KiB

    k_prep  <<<56, 256, 0, stream>>>(verts, tex, uv, tv, faces, frP, vattr);
    k_sort  <<<NB, 1024, 0, stream>>>(frP, rFace, binData);
    k_bin   <<<512, 64, 0, stream>>>(binData, list, listCnt);
    k_raster<<<NB * 1024, 64, 0, stream>>>(rFace, list, listCnt, faces, vattr, out);
}

// Round 7
// 129.628 us; speedup vs baseline: 1.5283x; 1.5283x over previous
//
#include <hip/hip_runtime.h>

#define HWD 256
#define NB 2
#define NV 5023
#define NF 2048

// ws layout:
//  zk    @ 0x000000  131072 * 8B = 1 MiB
//  frP   @ 0x100000  4096 * 64B  = 256 KiB  (16 floats per face, batch-major)
//  vattr @ 0x140000  10046*6*4B  = 236 KiB  (region 256 KiB)
//  rFace @ 0x180000  4096 * 64B  = 256 KiB  (bucket-ordered, segment-major records)
//  hist  @ 0x1C0000  512 * 4B

__device__ __forceinline__ float pix_coord(int i) {
    return ((float)i + 0.5f) * 0.0078125f - 1.0f;   // exact fp32
}

__device__ __forceinline__ int z_bucket(float zmax) {
    int k = (int)((1.0f - zmax) * 128.0f);
    return min(max(k, 0), 255);
}

// frP fields: 0 dy12, 1 dx21, 2 x2, 3 y2, 4 dy20, 5 dx02, 6 inv, 7 z0, 8 z1, 9 z2,
//             10 bbx, 11 bby, 12 denom, 13 zmax
__global__ __launch_bounds__(256) void k_prep(const float* __restrict__ verts,
                                              const float* __restrict__ tex,
                                              const float* __restrict__ uv,
                                              const float* __restrict__ tv,
                                              const int* __restrict__ faces,
                                              float* __restrict__ frP,
                                              float* __restrict__ vattr,
                                              unsigned long long* __restrict__ zk,
                                              unsigned int* __restrict__ hist) {
    int blk = blockIdx.x, tid = threadIdx.x;
    if (blk < 512) {                      // ---- zk init ----
        zk[blk * 256 + tid] = (0x407FFFFFull << 32) | 0x80000000ull;
        return;
    }
    if (blk < 552) {                      // ---- per-vertex attributes ----
        int i = (blk - 512) * 256 + tid;
        if (i >= NB * NV) return;
        int b = i / NV, v = i - b * NV;
        float u = __fmul_rn(uv[2 * v + 0], 255.0f);
        float w = __fmul_rn(uv[2 * v + 1], 255.0f);
        float uf = floorf(u); uf = fminf(fmaxf(uf, 0.0f), 254.0f);
        float vf = floorf(w); vf = fminf(fmaxf(vf, 0.0f), 254.0f);
        int u0 = (int)uf, v0 = (int)vf;
        float fu = __fsub_rn(u, uf);
        float fv = __fsub_rn(w, vf);
        const float* t   = tex + (size_t)b * HWD * HWD * 3;
        const float* c00 = t + ((size_t)v0 * HWD + u0) * 3;
        const float* c01 = c00 + 3;
        const float* c10 = c00 + HWD * 3;
        const float* c11 = c10 + 3;
        float gu = 1.0f - fu, gv = 1.0f - fv;
        float* o = vattr + (size_t)i * 6;
        for (int c = 0; c < 3; ++c) {
            float l0 = c00[c] * gu + c01[c] * fu;
            float l1 = c10[c] * gu + c11[c] * fu;
            o[c] = l0 * gv + l1 * fv;
        }
        const float* vp = verts + ((size_t)b * NV + v) * 3;
        o[3] = vp[0]; o[4] = vp[1]; o[5] = vp[2];
        return;
    }
    // ---- per-face setup + z-bucket histogram ----
    int i = (blk - 552) * 256 + tid;
    if (i >= NB * NF) return;
    int b = i / NF, f = i - b * NF;
    int i0 = faces[3 * f + 0], i1 = faces[3 * f + 1], i2 = faces[3 * f + 2];
    const float* base = tv + (size_t)b * NV * 3;
    float x0 = base[3 * i0 + 0], y0 = base[3 * i0 + 1], z0 = base[3 * i0 + 2];
    float x1 = base[3 * i1 + 0], y1 = base[3 * i1 + 1], z1 = base[3 * i1 + 2];
    float x2 = base[3 * i2 + 0], y2 = base[3 * i2 + 1], z2 = base[3 * i2 + 2];

    float dy12 = __fsub_rn(y1, y2);
    float dx21 = __fsub_rn(x2, x1);
    float dy20 = __fsub_rn(y2, y0);
    float dx02 = __fsub_rn(x0, x2);
    float denom = __fadd_rn(__fmul_rn(dy12, __fsub_rn(x0, x2)),
                            __fmul_rn(dx21, __fsub_rn(y0, y2)));
    bool valid = fabsf(denom) > 1e-8f;

    int xlo = 1, xhi = 0, ylo = 1, yhi = 0;
    if (valid) {
        if (fabsf(denom) < 1e-3f) {
            xlo = 0; xhi = 255; ylo = 0; yhi = 255;
        } else {
            float xmn = fminf(x0, fminf(x1, x2)), xmx = fmaxf(x0, fmaxf(x1, x2));
            float ymn = fminf(y0, fminf(y1, y2)), ymx = fmaxf(y0, fmaxf(y1, y2));
            xlo = (int)floorf((xmn + 1.0f) * 128.0f - 0.5f) - 1;
            xhi = (int)ceilf ((xmx + 1.0f) * 128.0f - 0.5f) + 1;
            ylo = (int)floorf((ymn + 1.0f) * 128.0f - 0.5f) - 1;
            yhi = (int)ceilf ((ymx + 1.0f) * 128.0f - 0.5f) + 1;
            xlo = max(xlo, 0); ylo = max(ylo, 0);
            xhi = min(xhi, 255); yhi = min(yhi, 255);
            if (xhi < xlo || yhi < ylo) { xlo = 1; xhi = 0; ylo = 1; yhi = 0; }
        }
    }
    float zmax = valid ? fmaxf(z0, fmaxf(z1, z2)) : -2.0f;
    float* o = frP + (size_t)i * 16;
    o[0] = dy12; o[1] = dx21; o[2] = x2; o[3] = y2;
    o[4] = dy20; o[5] = dx02; o[6] = valid ? (1.0f / denom) : 0.0f;
    o[7] = z0; o[8] = z1; o[9] = z2;
    ((unsigned int*)o)[10] = (unsigned)xlo | ((unsigned)xhi << 16);
    ((unsigned int*)o)[11] = (unsigned)ylo | ((unsigned)yhi << 16);
    o[12] = denom;
    o[13] = zmax;
    atomicAdd(&hist[b * 256 + z_bucket(zmax)], 1u);
}

// single block: exclusive scan of 512 bucket counts, scatter faces to bucket-ordered
// segment-major rFace records.
// rFace record (16 floats): 0 bbx, 1 bby, 2 fidbits(fid | skip<<16), 3 ubound,
//                           4 dy12, 5 dx21, 6 x2, 7 y2, 8 dy20, 9 dx02, 10 inv,
//                           11 z0, 12 z1, 13 z2, 14 15 pad
__global__ __launch_bounds__(1024) void k_scatter(const float* __restrict__ frP,
                                                  const unsigned int* __restrict__ hist,
                                                  float* __restrict__ rFace) {
    int tid = threadIdx.x;
    __shared__ unsigned int a[512];
    __shared__ unsigned int cur[512];
    unsigned int v = 0;
    if (tid < 512) { v = hist[tid]; a[tid] = v; }
    __syncthreads();
    for (int off = 1; off < 512; off <<= 1) {
        unsigned int t = 0;
        if (tid < 512 && tid >= off) t = a[tid - off];
        __syncthreads();
        if (tid < 512) a[tid] += t;
        __syncthreads();
    }
    if (tid < 512) cur[tid] = a[tid] - v;   // exclusive scan (global over b0 then b1)
    __syncthreads();

    for (int i = tid; i < NB * NF; i += 1024) {
        const float* o = frP + (size_t)i * 16;
        int b = i >> 11, fid = i & (NF - 1);
        float zmax = o[13];
        int k = z_bucket(zmax);
        unsigned int p = atomicAdd(&cur[b * 256 + k], 1u);   // p in [b*2048, b*2048+2048)
        unsigned int rank = p - (unsigned)(b * NF);
        unsigned int slot = (rank & 7u) * 256u + (rank >> 3);  // segment-major
        float* rf = rFace + (((size_t)b * NF + slot) << 4);
        bool skip = fabsf(o[12]) < 1e-3f;
        rf[0] = o[10]; rf[1] = o[11];
        rf[2] = __uint_as_float((unsigned)fid | ((unsigned)skip << 16));
        rf[3] = 1.0f - (float)k * 0.0078125f + 1e-6f;        // ubound >= zmax of bucket
        rf[4] = o[0]; rf[5] = o[1]; rf[6] = o[2]; rf[7] = o[3];
        rf[8] = o[4]; rf[9] = o[5]; rf[10] = o[6]; rf[11] = o[7];
        rf[12] = o[8]; rf[13] = o[9]; rf[14] = 0.0f; rf[15] = 0.0f;
    }
}

// block = (b, tile, seg): self-bin 256 interleaved-rank candidates into LDS,
// then pixel-per-thread raster with early-z break; one atomicMax per pixel.
__global__ __launch_bounds__(256) void k_raster(const float* __restrict__ rFace,
                                                unsigned long long* __restrict__ zk) {
    int bid  = blockIdx.x;
    int tile = bid & 255;
    int seg  = (bid >> 8) & 7;
    int b    = bid >> 11;
    int tid = threadIdx.x, wave = tid >> 6, lane = tid & 63;

    __shared__ float fdat[256 * 20];      // 20 KiB, stride 20 breaks bank alignment
    __shared__ unsigned int cntw[4];
    __shared__ float redmin[4];

    int tlx = tile & 15, tly = tile >> 4;

    // ---- self-bin: thread t tests candidate k=t of this segment ----
    {
        int slot = seg * 256 + tid;
        const float4* src = (const float4*)(rFace + (((size_t)b * NF + slot) << 4));
        float4 h = src[0], g0 = src[1], g1 = src[2], g2 = src[3];
        unsigned int bbx = __float_as_uint(h.x), bby = __float_as_uint(h.y);
        int xlo = (int)(bbx & 0xffffu), xhi = (int)(bbx >> 16);
        int ylo = (int)(bby & 0xffffu), yhi = (int)(bby >> 16);
        int pxlo = tlx << 4, pxhi = pxlo + 15, pylo = tly << 4, pyhi = pylo + 15;
        bool keep = (xhi >= xlo) && (xlo <= pxhi) && (xhi >= pxlo)
                                 && (ylo <= pyhi) && (yhi >= pylo);
        bool skip = (__float_as_uint(h.z) >> 16) != 0u;
        if (keep && !skip) {
            float inv = g1.z, x2 = g0.z, y2 = g0.w;
            float A0 = g0.x * inv, B0 = g0.y * inv;
            float A1 = g1.x * inv, B1 = g1.y * inv;
            float C = A0 + A1, D = B0 + B1;
            float x0n = pix_coord(pxlo), x1n = pix_coord(pxhi);
            float y0n = pix_coord(pylo), y1n = pix_coord(pyhi);
            float w0m = A0 * ((A0 > 0.f ? x1n : x0n) - x2) + B0 * ((B0 > 0.f ? y1n : y0n) - y2);
            float w1m = A1 * ((A1 > 0.f ? x1n : x0n) - x2) + B1 * ((B1 > 0.f ? y1n : y0n) - y2);
            float w2m = 1.0f - (C * ((C > 0.f ? x0n : x1n) - x2) + D * ((D > 0.f ? y0n : y1n) - y2));
            keep = (w0m >= -0.02f) && (w1m >= -0.02f) && (w2m >= -0.02f);
        }
        unsigned long long mask = __ballot(keep);
        if (keep) {
            int pos = __popcll(mask & ((1ull << lane) - 1ull));
            float* dst = &fdat[(size_t)(wave * 64 + pos) * 20];
            ((float4*)dst)[0] = h; ((float4*)dst)[1] = g0;
            ((float4*)dst)[2] = g1; ((float4*)dst)[3] = g2;
        }
        if (lane == 0) cntw[wave] = (unsigned int)__popcll(mask);
    }
    __syncthreads();

    // ---- raster ----
    int px = (tlx << 4) + (tid & 15), py = (tly << 4) + (tid >> 4);
    float pxf = pix_coord(px), pyf = pix_coord(py);
    unsigned long long best = 0ull;
    float curz = -1.0f;
    bool done = false;

    for (int w = 0; w < 4 && !done; ++w) {
        int n = (int)cntw[w];
        for (int j = 0; j < n; ++j) {
            if ((j & 15) == 0) {
                float m = curz;
                #pragma unroll
                for (int off = 1; off < 64; off <<= 1) m = fminf(m, __shfl_xor(m, off));
                __syncthreads();
                if (lane == 0) redmin[wave] = m;
                __syncthreads();
                float mb = fminf(fminf(redmin[0], redmin[1]), fminf(redmin[2], redmin[3]));
                float ub = fdat[(size_t)(w * 64 + j) * 20 + 3];
                if (ub < mb - 1e-5f) { done = true; break; }
            }
            const float* fp = &fdat[(size_t)(w * 64 + j) * 20];
            float x2 = fp[6], y2 = fp[7];
            float t0 = __fsub_rn(pxf, x2);
            float t1 = __fsub_rn(pyf, y2);
            float w0 = __fmul_rn(__fadd_rn(__fmul_rn(fp[4], t0), __fmul_rn(fp[5], t1)), fp[10]);
            float w1 = __fmul_rn(__fadd_rn(__fmul_rn(fp[8], t0), __fmul_rn(fp[9], t1)), fp[10]);
            float w2 = __fsub_rn(__fsub_rn(1.0f, w0), w1);
            if (w0 >= 0.0f && w1 >= 0.0f && w2 >= 0.0f) {
                float z = __fadd_rn(__fadd_rn(__fmul_rn(w0, fp[11]), __fmul_rn(w1, fp[12])),
                                    __fmul_rn(w2, fp[13]));
                unsigned int fid = __float_as_uint(fp[2]) & 0xFFFFu;
                unsigned int ub32 = __float_as_uint(z);
                unsigned int hi = ub32 ^ ((unsigned int)(((int)ub32) >> 31) | 0x80000000u);
                unsigned long long key = ((unsigned long long)hi << 32)
                                       | (unsigned long long)(0x7FFFFFFFu - fid);
                if (key > best) { best = key; curz = z; }
            }
        }
    }

    if (best) {
        int pix = (b << 16) + py * HWD + px;
        unsigned long long cur = zk[pix];
        if (best > cur) atomicMax(&zk[pix], best);
    }
}

__global__ __launch_bounds__(256) void k_shade(const unsigned long long* __restrict__ zk,
                                               const float* __restrict__ frP,
                                               const int* __restrict__ faces,
                                               const float* __restrict__ vattr,
                                               float* __restrict__ out) {
    int i = blockIdx.x * 256 + threadIdx.x;
    int b = i >> 16;
    int pix = i & 0xFFFF;
    unsigned long long key = zk[i];
    unsigned int lo = (unsigned int)key;
    unsigned int hi = (unsigned int)(key >> 32);

    float img[6] = {0, 0, 0, 0, 0, 0};
    float alpha, fidf, zout;
    if (lo > 0x7FFFFFFFu) {
        alpha = 0.0f; fidf = -1.0f; zout = -1.0f;
    } else {
        int f = (int)(0x7FFFFFFFu - lo);
        unsigned int zb32 = (hi & 0x80000000u) ? (hi & 0x7FFFFFFFu) : ~hi;
        zout = __uint_as_float(zb32);
        alpha = 1.0f;
        fidf = (float)f;
        const float* fp = frP + ((size_t)(b * NF + f)) * 16;
        int px = pix & 0xFF, py = pix >> 8;
        float t0 = __fsub_rn(pix_coord(px), fp[2]);
        float t1 = __fsub_rn(pix_coord(py), fp[3]);
        float w0 = __fmul_rn(__fadd_rn(__fmul_rn(fp[0], t0), __fmul_rn(fp[1], t1)), fp[6]);
        float w1 = __fmul_rn(__fadd_rn(__fmul_rn(fp[4], t0), __fmul_rn(fp[5], t1)), fp[6]);
        float w2 = __fsub_rn(__fsub_rn(1.0f, w0), w1);
        int i0 = faces[3 * f + 0], i1 = faces[3 * f + 1], i2 = faces[3 * f + 2];
        const float* a0 = vattr + ((size_t)b * NV + i0) * 6;
        const float* a1 = vattr + ((size_t)b * NV + i1) * 6;
        const float* a2 = vattr + ((size_t)b * NV + i2) * 6;
        for (int c = 0; c < 6; ++c)
            img[c] = __fadd_rn(__fadd_rn(__fmul_rn(w0, a0[c]), __fmul_rn(w1, a1[c])),
                               __fmul_rn(w2, a2[c]));
    }

    const size_t plane = (size_t)HWD * HWD;
    for (int c = 0; c < 6; ++c)
        out[((size_t)b * 6 + c) * plane + pix] = img[c];
    out[786432 + i]  = alpha;
    out[917504 + i]  = fidf;
    out[1048576 + i] = zout;
}

extern "C" void kernel_launch(void* const* d_in, const int* in_sizes, int n_in,
                              void* d_out, int out_size, void* d_ws, size_t ws_size,
                              hipStream_t stream) {
    (void)in_sizes; (void)n_in; (void)out_size; (void)ws_size;
    const float* verts = (const float*)d_in[0];
    const float* tv    = (const float*)d_in[1];
    const float* tex   = (const float*)d_in[2];
    const float* uv    = (const float*)d_in[3];
    const int*   faces = (const int*)d_in[4];
    float* out = (float*)d_out;

    char* ws = (char*)d_ws;
    unsigned long long* zk    = (unsigned long long*)ws;            // 1 MiB
    float*              frP   = (float*)(ws + 0x100000);            // 256 KiB
    float*              vattr = (float*)(ws + 0x140000);            // 256 KiB
    float*              rFace = (float*)(ws + 0x180000);            // 256 KiB
    unsigned int*       hist  = (unsigned int*)(ws + 0x1C0000);     // 2 KiB

    hipMemsetAsync(hist, 0, 512 * sizeof(unsigned int), stream);
    k_prep   <<<568, 256, 0, stream>>>(verts, tex, uv, tv, faces, frP, vattr, zk, hist);
    k_scatter<<<1, 1024, 0, stream>>>(frP, hist, rFace);
    k_raster <<<NB * 8 * 256, 256, 0, stream>>>(rFace, zk);
    k_shade  <<<512, 256, 0, stream>>>(zk, frP, faces, vattr, out);
}